// Round 6
// baseline (1452.665 us; speedup 1.0000x reference)
//
#include <hip/hip_runtime.h>
#include <stdint.h>

typedef unsigned short u16;
typedef unsigned int u32;
typedef unsigned long long u64;

#define NB 16
#define NP 4096
#define NCH 64
#define NS 1024
#define NK 32
#define H1D 128
#define H2D 256
#define KP1 96
#define LDA 104
#define LDH 136
#define OUTOFF (NB * NS * H2D) /* 4194304 */

typedef __attribute__((ext_vector_type(8))) short bfrag;
typedef __attribute__((ext_vector_type(4))) float facc4;

__device__ __forceinline__ u16 f2bf(float f) {
  u32 u = __float_as_uint(f);
  u += 0x7FFFu + ((u >> 16) & 1u);
  return (u16)(u >> 16);
}

// Exactly replicates jnp.sum((a-b)**2, axis=-1) for 3 elems: ((dx*dx+dy*dy)+dz*dz),
// no fma contraction (XLA emits plain mul/add; hipcc honors the pragma).
__device__ __forceinline__ float dist2(float ax, float ay, float az,
                                       float bx, float by, float bz) {
#pragma clang fp contract(off)
  float dx = ax - bx, dy = ay - by, dz = az - bz;
  return dx * dx + dy * dy + dz * dz;
}

// Full-wave (64-lane) max via DPP on the VALU pipe; result returned uniform.
__device__ __forceinline__ float wave_max_f32(float v) {
  const int NI = (int)0xFF800000u;  // -inf bits = identity for max
  v = fmaxf(v, __int_as_float(__builtin_amdgcn_update_dpp(NI, __float_as_int(v), 0x111, 0xf, 0xf, false)));
  v = fmaxf(v, __int_as_float(__builtin_amdgcn_update_dpp(NI, __float_as_int(v), 0x112, 0xf, 0xf, false)));
  v = fmaxf(v, __int_as_float(__builtin_amdgcn_update_dpp(NI, __float_as_int(v), 0x114, 0xf, 0xf, false)));
  v = fmaxf(v, __int_as_float(__builtin_amdgcn_update_dpp(NI, __float_as_int(v), 0x118, 0xf, 0xf, false)));
  v = fmaxf(v, __int_as_float(__builtin_amdgcn_update_dpp(NI, __float_as_int(v), 0x142, 0xa, 0xf, false)));
  v = fmaxf(v, __int_as_float(__builtin_amdgcn_update_dpp(NI, __float_as_int(v), 0x143, 0xc, 0xf, false)));
  return __int_as_float(__builtin_amdgcn_readlane(__float_as_int(v), 63));
}

// Full-wave (64-lane) min of u32 via DPP; result returned uniform.
__device__ __forceinline__ u32 wave_min_u32(u32 v) {
  u32 t;
  t = (u32)__builtin_amdgcn_update_dpp(-1, (int)v, 0x111, 0xf, 0xf, false); v = t < v ? t : v;
  t = (u32)__builtin_amdgcn_update_dpp(-1, (int)v, 0x112, 0xf, 0xf, false); v = t < v ? t : v;
  t = (u32)__builtin_amdgcn_update_dpp(-1, (int)v, 0x114, 0xf, 0xf, false); v = t < v ? t : v;
  t = (u32)__builtin_amdgcn_update_dpp(-1, (int)v, 0x118, 0xf, 0xf, false); v = t < v ? t : v;
  t = (u32)__builtin_amdgcn_update_dpp(-1, (int)v, 0x142, 0xa, 0xf, false); v = t < v ? t : v;
  t = (u32)__builtin_amdgcn_update_dpp(-1, (int)v, 0x143, 0xc, 0xf, false); v = t < v ? t : v;
  return (u32)__builtin_amdgcn_readlane((int)v, 63);
}

// One step of a 4-slot quad_perm butterfly carrying (key, x, y, z).
#define QUAD_MAX_STEP(CTRL)                                                           \
  {                                                                                   \
    const u32 plo = (u32)__builtin_amdgcn_update_dpp(0, (int)klo, (CTRL), 0xf, 0xf, true); \
    const u32 phi = (u32)__builtin_amdgcn_update_dpp(0, (int)khi, (CTRL), 0xf, 0xf, true); \
    const u32 pqx = (u32)__builtin_amdgcn_update_dpp(0, (int)qxu, (CTRL), 0xf, 0xf, true); \
    const u32 pqy = (u32)__builtin_amdgcn_update_dpp(0, (int)qyu, (CTRL), 0xf, 0xf, true); \
    const u32 pqz = (u32)__builtin_amdgcn_update_dpp(0, (int)qzu, (CTRL), 0xf, 0xf, true); \
    const u64 ok = ((u64)phi << 32) | plo;                                            \
    const u64 mk = ((u64)khi << 32) | klo;                                            \
    if (ok > mk) { klo = plo; khi = phi; qxu = pqx; qyu = pqy; qzu = pqz; }           \
  }

// ---------------- K0: transpose + pad + bf16-convert weights ----------------
__global__ void setup_kernel(const float* __restrict__ W1, const float* __restrict__ W2,
                             u16* __restrict__ W1T, u16* __restrict__ W2T) {
  int idx = blockIdx.x * 256 + threadIdx.x;
  if (idx < H1D * KP1) {
    int n = idx / KP1, k = idx % KP1;
    W1T[idx] = f2bf(k < 67 ? W1[k * H1D + n] : 0.f);
  } else if (idx < H1D * KP1 + H2D * H1D) {
    int j = idx - H1D * KP1;
    int n = j / H1D, k = j % H1D;
    W2T[j] = f2bf(W2[k * H2D + n]);
  }
}

// ---------------- K1: farthest point sampling ----------------
// 2 INDEPENDENT clouds per 512-thread block (waves 0-3 / 4-7), NO barriers in
// the loop: cross-wave exchange is a tagged LDS record + spin-poll, so the two
// clouds' latency chains interleave freely on the shared SIMDs (round-4's
// lockstep failure was the shared __syncthreads; this removes it).
// Record slot s (2-deep): payload uint4 {x,y,z,d2bits} at [0..3], then fence,
// then tag (i<<14)|(enc<<2)|wave at [4]. Lap-safety: a wave produces iter i's
// record only after consuming iter i-1, which required every wave's i-1 record,
// which required them consuming i-2 from this slot.
__global__ __launch_bounds__(512) void fps_kernel(const float* __restrict__ pos,
                                                  int* __restrict__ samp,
                                                  float* __restrict__ pos_s) {
  __shared__ float4 plds[2 * NP];              // 128 KiB: both clouds' pos
  __shared__ __align__(16) u32 recs[2][2][4][8];  // [cloud][slot][wave][8 words]
  const int tid = threadIdx.x;
  const int lane = tid & 63;
  const int cl = tid >> 8;        // cloud within block
  const int wc = (tid >> 6) & 3;  // wave within cloud
  const int tt = tid & 255;       // thread id within cloud
  const int cb = blockIdx.x * 2 + cl;  // global cloud id
  if (tid < 16) recs[tid >> 3][(tid >> 2) & 1][tid & 3][4] = 0xFFFFFFFFu;
  for (int k = tid; k < 2 * NP; k += 512) {
    const int cc = k >> 12, p = k & (NP - 1);
    const float* src = pos + ((size_t)(blockIdx.x * 2 + cc) * NP + p) * 3;
    plds[k] = make_float4(src[0], src[1], src[2], 0.f);
  }
  __syncthreads();  // the only block-wide barrier (staging + tag init)

  float px[16], py[16], pz[16], d[16];
  const float4 q0 = plds[cl * NP];
  float bv = -1.f;
  int bj = 0;
#pragma unroll
  for (int j = 0; j < 16; ++j) {
    const float4 p4 = plds[cl * NP + j * 256 + tt];
    px[j] = p4.x; py[j] = p4.y; pz[j] = p4.z;
    d[j] = dist2(p4.x, p4.y, p4.z, q0.x, q0.y, q0.z);
    const bool cg = d[j] > bv;  // ascending j, strict > => first occurrence
    bv = cg ? d[j] : bv;
    bj = cg ? j : bj;
  }
  if (tt == 0) {
    samp[cb * NS] = 0;
    pos_s[(size_t)cb * NS * 3 + 0] = q0.x;
    pos_s[(size_t)cb * NS * 3 + 1] = q0.y;
    pos_s[(size_t)cb * NS * 3 + 2] = q0.z;
  }

  for (int i = 1; i < NS; ++i) {
    const u32 gidx = (u32)(bj * 256 + tt);
    const float4 cpos = plds[cl * NP + gidx];  // speculative: my candidate's pos
    // wave-level argmax: value chain then first-occurrence index chain
    const float wmax = wave_max_f32(bv);
    const u32 cand = (bv == wmax) ? gidx : 0xFFFFFFFFu;
    const u32 widx = wave_min_u32(cand);
    // unique winning lane publishes the record
    if (bv == wmax && gidx == widx) {
      *(uint4*)&recs[cl][i & 1][wc][0] =
          make_uint4(__float_as_uint(cpos.x), __float_as_uint(cpos.y),
                     __float_as_uint(cpos.z), __float_as_uint(wmax));
      __threadfence_block();
      *(volatile u32*)&recs[cl][i & 1][wc][4] =
          ((u32)i << 14) | ((4095u - widx) << 2) | (u32)wc;
    }
    // spin-poll all 4 wave slots (lane&3 spreads lanes over slots)
    const int slot = lane & 3;
    volatile u32* tp = &recs[cl][i & 1][slot][4];
    u32 t;
    do { t = *tp; } while (!__all((int)((t >> 14) == (u32)i)));
    __threadfence_block();
    const uint4 pay = *(const uint4*)&recs[cl][i & 1][slot][0];
    u32 klo = t, khi = pay.w;  // key = (d2bits<<32)|(i<<14|enc<<2|wv)
    u32 qxu = pay.x, qyu = pay.y, qzu = pay.z;
    QUAD_MAX_STEP(0xB1)  // quad_perm [1,0,3,2]
    QUAD_MAX_STEP(0x4E)  // quad_perm [2,3,0,1]
    const float qx = __uint_as_float(qxu);
    const float qy = __uint_as_float(qyu);
    const float qz = __uint_as_float(qzu);
    if (tt == 0) {
      const int gi = 4095 - (int)((klo >> 2) & 0xFFFu);
      samp[cb * NS + i] = gi;
      pos_s[((size_t)cb * NS + i) * 3 + 0] = qx;
      pos_s[((size_t)cb * NS + i) * 3 + 1] = qy;
      pos_s[((size_t)cb * NS + i) * 3 + 2] = qz;
    }
    // fused d-update + next local argmax
    bv = -1.f; bj = 0;
#pragma unroll
    for (int j = 0; j < 16; ++j) {
      d[j] = fminf(d[j], dist2(px[j], py[j], pz[j], qx, qy, qz));
      const bool cg = d[j] > bv;
      bv = cg ? d[j] : bv;
      bj = cg ? j : bj;
    }
  }
}

// ---------------- K2: ball query, exact top-K=32 by (d2, idx) key ----------------
__global__ __launch_bounds__(256) void ballq_kernel(const float* __restrict__ pos,
                                                    const int* __restrict__ samp,
                                                    int* __restrict__ nbr) {
  __shared__ u64 buf[4][512];
  const int lane = threadIdx.x & 63, wv = threadIdx.x >> 6;
  const int sg = blockIdx.x * 4 + wv;
  const int b = sg >> 10;
  const int nc = samp[sg];
  const float* pb = pos + (size_t)b * NP * 3;
  const float cx = pb[nc * 3 + 0], cy = pb[nc * 3 + 1], cz = pb[nc * 3 + 2];
  const float r2 = (float)(0.2 * 0.2);  // matches Python RADIUS*RADIUS -> f32
  int V = 0;
  for (int c = 0; c < 64; ++c) {
    const int i = c * 64 + lane;
    const float d2v = dist2(cx, cy, cz, pb[i * 3 + 0], pb[i * 3 + 1], pb[i * 3 + 2]);
    const bool valid = d2v <= r2;
    const u64 bal = __ballot(valid);
    if (valid) {
      const int rank = __popcll(bal & ((1ull << lane) - 1ull));
      const int p = V + rank;
      if (p < 512) buf[wv][p] = ((u64)__float_as_uint(d2v) << 32) | (u32)i;
    }
    V += __popcll(bal);
  }
  if (V > 512) V = 512;  // statistically unreachable (E[V]~137)
  u64 ck[8];
#pragma unroll
  for (int t = 0; t < 8; ++t) {
    const int p = t * 64 + lane;
    ck[t] = (p < V) ? buf[wv][p] : ~0ull;
  }
  u32 my = 0, pad = 0;
  for (int e = 0; e < 32; ++e) {
    u64 lm = ck[0];
#pragma unroll
    for (int t = 1; t < 8; ++t) lm = (ck[t] < lm) ? ck[t] : lm;
#pragma unroll
    for (int m = 1; m < 64; m <<= 1) {
      const u64 o = __shfl_xor(lm, m);
      lm = (o < lm) ? o : lm;
    }
    if (e == 0) pad = (u32)lm;  // centroid itself: always valid
    const u32 widx = (lm == ~0ull) ? pad : (u32)lm;
    if (lane == e) my = widx;
#pragma unroll
    for (int t = 0; t < 8; ++t)
      if (ck[t] == lm) ck[t] = ~0ull;
  }
  if (lane < 32) nbr[(size_t)sg * NK + lane] = (int)my;
}

// ---------------- K3: gather -> bf16 MFMA MLP -> maxpool ----------------
__global__ __launch_bounds__(256) void mlp_kernel(
    const float* __restrict__ x, const float* __restrict__ pos,
    const float* __restrict__ b1, const float* __restrict__ b2,
    const int* __restrict__ nbr, const u16* __restrict__ W1T,
    const u16* __restrict__ W2T, const float* __restrict__ pos_s,
    float* __restrict__ out) {
  __shared__ u16 A[128 * LDA];
  __shared__ u16 Hs[128 * LDH];
  const int ctr0 = blockIdx.x * 4;
  const int b = ctr0 >> 10;
  const int tid = threadIdx.x;
  {  // stage A tile: 128 rows x 96 cols bf16 (x | rel | zeros)
    const int row = tid >> 1, half = tid & 1;
    const int g = ctr0 + (row >> 5);
    const int n = nbr[(size_t)g * NK + (row & 31)];
    const float4* xr = (const float4*)(x + ((size_t)b * NP + n) * NCH + half * 32);
#pragma unroll
    for (int qq = 0; qq < 4; ++qq) {
      const float4 v0 = xr[2 * qq], v1 = xr[2 * qq + 1];
      uint4 wp;
      wp.x = (u32)f2bf(v0.x) | ((u32)f2bf(v0.y) << 16);
      wp.y = (u32)f2bf(v0.z) | ((u32)f2bf(v0.w) << 16);
      wp.z = (u32)f2bf(v1.x) | ((u32)f2bf(v1.y) << 16);
      wp.w = (u32)f2bf(v1.z) | ((u32)f2bf(v1.w) << 16);
      *(uint4*)&A[row * LDA + half * 32 + qq * 8] = wp;
    }
    if (half == 0) {
      const float rx = pos[((size_t)b * NP + n) * 3 + 0] - pos_s[(size_t)g * 3 + 0];
      const float ry = pos[((size_t)b * NP + n) * 3 + 1] - pos_s[(size_t)g * 3 + 1];
      const float rz = pos[((size_t)b * NP + n) * 3 + 2] - pos_s[(size_t)g * 3 + 2];
      uint4 wr;
      wr.x = (u32)f2bf(rx) | ((u32)f2bf(ry) << 16);
      wr.y = (u32)f2bf(rz);
      wr.z = 0; wr.w = 0;
      uint4 wz;
      wz.x = wz.y = wz.z = wz.w = 0;
      *(uint4*)&A[row * LDA + 64] = wr;
      *(uint4*)&A[row * LDA + 72] = wz;
      *(uint4*)&A[row * LDA + 80] = wz;
      *(uint4*)&A[row * LDA + 88] = wz;
    }
  }
  __syncthreads();
  const int lane = tid & 63, w = tid >> 6;
  const int r16 = lane & 15, g4 = lane >> 4;
  {  // layer 1: [128x96] @ [96x128] -> relu -> Hs bf16
    bfrag af[2][3];
#pragma unroll
    for (int mg2 = 0; mg2 < 2; ++mg2)
#pragma unroll
      for (int ks = 0; ks < 3; ++ks)
        af[mg2][ks] = *(const bfrag*)&A[((2 * w + mg2) * 16 + r16) * LDA + ks * 32 + g4 * 8];
#pragma unroll
    for (int ng = 0; ng < 8; ++ng) {
      const bfrag bw0 = *(const bfrag*)&W1T[(ng * 16 + r16) * KP1 + 0 + g4 * 8];
      const bfrag bw1 = *(const bfrag*)&W1T[(ng * 16 + r16) * KP1 + 32 + g4 * 8];
      const bfrag bw2 = *(const bfrag*)&W1T[(ng * 16 + r16) * KP1 + 64 + g4 * 8];
      facc4 a0 = {0.f, 0.f, 0.f, 0.f}, a1 = {0.f, 0.f, 0.f, 0.f};
      a0 = __builtin_amdgcn_mfma_f32_16x16x32_bf16(af[0][0], bw0, a0, 0, 0, 0);
      a0 = __builtin_amdgcn_mfma_f32_16x16x32_bf16(af[0][1], bw1, a0, 0, 0, 0);
      a0 = __builtin_amdgcn_mfma_f32_16x16x32_bf16(af[0][2], bw2, a0, 0, 0, 0);
      a1 = __builtin_amdgcn_mfma_f32_16x16x32_bf16(af[1][0], bw0, a1, 0, 0, 0);
      a1 = __builtin_amdgcn_mfma_f32_16x16x32_bf16(af[1][1], bw1, a1, 0, 0, 0);
      a1 = __builtin_amdgcn_mfma_f32_16x16x32_bf16(af[1][2], bw2, a1, 0, 0, 0);
      const float bias = b1[ng * 16 + r16];
#pragma unroll
      for (int r = 0; r < 4; ++r) {
        Hs[((2 * w + 0) * 16 + g4 * 4 + r) * LDH + ng * 16 + r16] = f2bf(fmaxf(a0[r] + bias, 0.f));
        Hs[((2 * w + 1) * 16 + g4 * 4 + r) * LDH + ng * 16 + r16] = f2bf(fmaxf(a1[r] + bias, 0.f));
      }
    }
  }
  __syncthreads();
  {  // layer 2 + maxpool: wave w owns centroid w (rows 32w..32w+31)
    bfrag hf[2][4];
#pragma unroll
    for (int mg2 = 0; mg2 < 2; ++mg2)
#pragma unroll
      for (int ks = 0; ks < 4; ++ks)
        hf[mg2][ks] = *(const bfrag*)&Hs[((2 * w + mg2) * 16 + r16) * LDH + ks * 32 + g4 * 8];
    const int gout = ctr0 + w;
#pragma unroll
    for (int ng = 0; ng < 16; ++ng) {
      facc4 a0 = {0.f, 0.f, 0.f, 0.f}, a1 = {0.f, 0.f, 0.f, 0.f};
#pragma unroll
      for (int ks = 0; ks < 4; ++ks) {
        const bfrag bw = *(const bfrag*)&W2T[(ng * 16 + r16) * H1D + ks * 32 + g4 * 8];
        a0 = __builtin_amdgcn_mfma_f32_16x16x32_bf16(hf[0][ks], bw, a0, 0, 0, 0);
        a1 = __builtin_amdgcn_mfma_f32_16x16x32_bf16(hf[1][ks], bw, a1, 0, 0, 0);
      }
      // max over the centroid's 32 rows; bias+relu commute with max
      float m0 = fmaxf(fmaxf(a0[0], a0[1]), fmaxf(a0[2], a0[3]));
      float m1 = fmaxf(fmaxf(a1[0], a1[1]), fmaxf(a1[2], a1[3]));
      float mm = fmaxf(m0, m1);
      mm = fmaxf(mm, __shfl_xor(mm, 16));
      mm = fmaxf(mm, __shfl_xor(mm, 32));
      const float ov = fmaxf(mm + b2[ng * 16 + r16], 0.f);
      if (lane < 16) out[(size_t)gout * H2D + ng * 16 + lane] = ov;
    }
  }
}

extern "C" void kernel_launch(void* const* d_in, const int* in_sizes, int n_in,
                              void* d_out, int out_size, void* d_ws, size_t ws_size,
                              hipStream_t stream) {
  const float* x = (const float*)d_in[0];
  const float* pos = (const float*)d_in[1];
  const float* W1 = (const float*)d_in[2];
  const float* b1 = (const float*)d_in[3];
  const float* W2 = (const float*)d_in[4];
  const float* b2 = (const float*)d_in[5];
  float* out = (float*)d_out;
  char* ws = (char*)d_ws;
  u16* W1T = (u16*)(ws + 0);           // 24576 B
  u16* W2T = (u16*)(ws + 24576);       // 65536 B
  int* samp = (int*)(ws + 90112);      // 65536 B
  int* nbr = (int*)(ws + 155648);      // 2 MiB
  float* pos_s = out + OUTOFF;

  setup_kernel<<<dim3(176), dim3(256), 0, stream>>>(W1, W2, W1T, W2T);
  fps_kernel<<<dim3(NB / 2), dim3(512), 0, stream>>>(pos, samp, pos_s);
  ballq_kernel<<<dim3(NB * NS / 4), dim3(256), 0, stream>>>(pos, samp, nbr);
  mlp_kernel<<<dim3(NB * NS / 4), dim3(256), 0, stream>>>(x, pos, b1, b2, nbr, W1T, W2T,
                                                          pos_s, out);
}

// Round 7
// 921.862 us; speedup vs baseline: 1.5758x; 1.5758x over previous
//
#include <hip/hip_runtime.h>
#include <stdint.h>

typedef unsigned short u16;
typedef unsigned int u32;
typedef unsigned long long u64;

#define NB 16
#define NP 4096
#define NCH 64
#define NS 1024
#define NK 32
#define H1D 128
#define H2D 256
#define KP1 96
#define LDA 104
#define LDH 136
#define OUTOFF (NB * NS * H2D) /* 4194304 */

typedef __attribute__((ext_vector_type(8))) short bfrag;
typedef __attribute__((ext_vector_type(4))) float facc4;

__device__ __forceinline__ u16 f2bf(float f) {
  u32 u = __float_as_uint(f);
  u += 0x7FFFu + ((u >> 16) & 1u);
  return (u16)(u >> 16);
}

// Exactly replicates jnp.sum((a-b)**2, axis=-1) for 3 elems: ((dx*dx+dy*dy)+dz*dz),
// no fma contraction (XLA emits plain mul/add; hipcc honors the pragma).
__device__ __forceinline__ float dist2(float ax, float ay, float az,
                                       float bx, float by, float bz) {
#pragma clang fp contract(off)
  float dx = ax - bx, dy = ay - by, dz = az - bz;
  return dx * dx + dy * dy + dz * dz;
}

// Full-wave (64-lane) max via DPP on the VALU pipe; result returned uniform.
__device__ __forceinline__ float wave_max_f32(float v) {
  const int NI = (int)0xFF800000u;  // -inf bits = identity for max
  v = fmaxf(v, __int_as_float(__builtin_amdgcn_update_dpp(NI, __float_as_int(v), 0x111, 0xf, 0xf, false)));
  v = fmaxf(v, __int_as_float(__builtin_amdgcn_update_dpp(NI, __float_as_int(v), 0x112, 0xf, 0xf, false)));
  v = fmaxf(v, __int_as_float(__builtin_amdgcn_update_dpp(NI, __float_as_int(v), 0x114, 0xf, 0xf, false)));
  v = fmaxf(v, __int_as_float(__builtin_amdgcn_update_dpp(NI, __float_as_int(v), 0x118, 0xf, 0xf, false)));
  v = fmaxf(v, __int_as_float(__builtin_amdgcn_update_dpp(NI, __float_as_int(v), 0x142, 0xa, 0xf, false)));
  v = fmaxf(v, __int_as_float(__builtin_amdgcn_update_dpp(NI, __float_as_int(v), 0x143, 0xc, 0xf, false)));
  return __int_as_float(__builtin_amdgcn_readlane(__float_as_int(v), 63));
}

// Full-wave (64-lane) min of u32 via DPP; result returned uniform.
__device__ __forceinline__ u32 wave_min_u32(u32 v) {
  u32 t;
  t = (u32)__builtin_amdgcn_update_dpp(-1, (int)v, 0x111, 0xf, 0xf, false); v = t < v ? t : v;
  t = (u32)__builtin_amdgcn_update_dpp(-1, (int)v, 0x112, 0xf, 0xf, false); v = t < v ? t : v;
  t = (u32)__builtin_amdgcn_update_dpp(-1, (int)v, 0x114, 0xf, 0xf, false); v = t < v ? t : v;
  t = (u32)__builtin_amdgcn_update_dpp(-1, (int)v, 0x118, 0xf, 0xf, false); v = t < v ? t : v;
  t = (u32)__builtin_amdgcn_update_dpp(-1, (int)v, 0x142, 0xa, 0xf, false); v = t < v ? t : v;
  t = (u32)__builtin_amdgcn_update_dpp(-1, (int)v, 0x143, 0xc, 0xf, false); v = t < v ? t : v;
  return (u32)__builtin_amdgcn_readlane((int)v, 63);
}

// ---------------- K0: transpose + pad + bf16-convert weights ----------------
__global__ void setup_kernel(const float* __restrict__ W1, const float* __restrict__ W2,
                             u16* __restrict__ W1T, u16* __restrict__ W2T) {
  int idx = blockIdx.x * 256 + threadIdx.x;
  if (idx < H1D * KP1) {
    int n = idx / KP1, k = idx % KP1;
    W1T[idx] = f2bf(k < 67 ? W1[k * H1D + n] : 0.f);
  } else if (idx < H1D * KP1 + H2D * H1D) {
    int j = idx - H1D * KP1;
    int n = j / H1D, k = j % H1D;
    W2T[j] = f2bf(W2[k * H2D + n]);
  }
}

// ---------------- K1: farthest point sampling (1 block per cloud) ----------------
// 256 threads = 4 waves (1/SIMD); 16 pts/thread in registers; DPP argmax reduce.
// (round-3 version verbatim: best measured 675 us; r4/r5/r6 restructures all lost)
__global__ __launch_bounds__(256) void fps_kernel(const float* __restrict__ pos,
                                                  int* __restrict__ samp,
                                                  float* __restrict__ pos_s) {
  __shared__ float4 plds[NP];      // 64 KiB: pos as float4 for b128 broadcast
  __shared__ __align__(16) u64 wkey[2][4];
  const int b = blockIdx.x;
  const int tid = threadIdx.x;
  const int lane = tid & 63, wv = tid >> 6;
  const float* pb = pos + (size_t)b * NP * 3;
  for (int k = tid; k < NP; k += 256)
    plds[k] = make_float4(pb[k * 3 + 0], pb[k * 3 + 1], pb[k * 3 + 2], 0.f);
  __syncthreads();

  float px[16], py[16], pz[16], d[16];
  const float4 q0 = plds[0];
  float bv = -1.f;
  int bj = 0;
#pragma unroll
  for (int j = 0; j < 16; ++j) {
    const float4 p4 = plds[j * 256 + tid];
    px[j] = p4.x; py[j] = p4.y; pz[j] = p4.z;
    d[j] = dist2(p4.x, p4.y, p4.z, q0.x, q0.y, q0.z);
    const bool cg = d[j] > bv;  // ascending j, strict > => first occurrence
    bv = cg ? d[j] : bv;
    bj = cg ? j : bj;
  }
  if (tid == 0) {
    samp[b * NS] = 0;
    pos_s[(size_t)b * NS * 3 + 0] = q0.x;
    pos_s[(size_t)b * NS * 3 + 1] = q0.y;
    pos_s[(size_t)b * NS * 3 + 2] = q0.z;
  }

  for (int i = 1; i < NS; ++i) {
    // phase 1: wave max value (VALU DPP, no LDS)
    const float wmax = wave_max_f32(bv);
    // phase 2: exact first-occurrence index among tied lanes
    const u32 cand = (bv == wmax) ? (u32)(bj * 256 + tid) : 0xFFFFFFFFu;
    const u32 widx = wave_min_u32(cand);
    if (lane == 0)
      wkey[i & 1][wv] = ((u64)__float_as_uint(wmax) << 32) | (u64)(4095u - widx);
    __syncthreads();
    // cross-wave: 2 overlapped 16B LDS reads + 3 u64 compares, all threads
    const ulonglong2 k01 = *(const ulonglong2*)&wkey[i & 1][0];
    const ulonglong2 k23 = *(const ulonglong2*)&wkey[i & 1][2];
    u64 g = k01.x;
    g = k01.y > g ? k01.y : g;
    g = k23.x > g ? k23.x : g;
    g = k23.y > g ? k23.y : g;
    const int gi = __builtin_amdgcn_readfirstlane(4095 - (int)((u32)g & 0xFFFu));
    const float4 q = plds[gi];  // uniform address -> broadcast read
    if (tid == 0) {
      samp[b * NS + i] = gi;
      pos_s[((size_t)b * NS + i) * 3 + 0] = q.x;
      pos_s[((size_t)b * NS + i) * 3 + 1] = q.y;
      pos_s[((size_t)b * NS + i) * 3 + 2] = q.z;
    }
    // fused d-update + next local argmax
    bv = -1.f; bj = 0;
#pragma unroll
    for (int j = 0; j < 16; ++j) {
      d[j] = fminf(d[j], dist2(px[j], py[j], pz[j], q.x, q.y, q.z));
      const bool cg = d[j] > bv;
      bv = cg ? d[j] : bv;
      bj = cg ? j : bj;
    }
  }
}

// ---------------- K2: ball query, exact top-K=32 by (d2, idx) key ----------------
// u32 split-key extraction: DPP v_min_u32 chains (VALU) replace the u64
// shfl_xor butterfly (LDS pipe). Tie-break remains exact lexicographic.
__global__ __launch_bounds__(256) void ballq_kernel(const float* __restrict__ pos,
                                                    const int* __restrict__ samp,
                                                    int* __restrict__ nbr) {
  __shared__ u64 buf[4][256];
  const int lane = threadIdx.x & 63, wv = threadIdx.x >> 6;
  const int sg = blockIdx.x * 4 + wv;
  const int b = sg >> 10;
  const int nc = samp[sg];
  const float* pb = pos + (size_t)b * NP * 3;
  const float cx = pb[nc * 3 + 0], cy = pb[nc * 3 + 1], cz = pb[nc * 3 + 2];
  const float r2 = (float)(0.2 * 0.2);  // matches Python RADIUS*RADIUS -> f32
  int V = 0;
  for (int c = 0; c < 64; ++c) {
    const int i = c * 64 + lane;
    const float d2v = dist2(cx, cy, cz, pb[i * 3 + 0], pb[i * 3 + 1], pb[i * 3 + 2]);
    const bool valid = d2v <= r2;
    const u64 bal = __ballot(valid);
    if (valid) {
      const int rank = __popcll(bal & ((1ull << lane) - 1ull));
      const int p = V + rank;
      if (p < 256) buf[wv][p] = ((u64)__float_as_uint(d2v) << 32) | (u32)i;
    }
    V += __popcll(bal);
  }
  if (V > 256) V = 256;  // P(V>256) ~ 1e-21 per query (mean 137, sd 11.5)
  u32 kd[4], ki[4];
#pragma unroll
  for (int t = 0; t < 4; ++t) {
    const int p = t * 64 + lane;
    const u64 v = (p < V) ? buf[wv][p] : ~0ull;
    kd[t] = (u32)(v >> 32);
    ki[t] = (u32)v;
  }
  u32 my = 0, pad = 0;
  for (int e = 0; e < 32; ++e) {
    // global min d2-bits
    u32 m0 = kd[0] < kd[1] ? kd[0] : kd[1];
    u32 m1 = kd[2] < kd[3] ? kd[2] : kd[3];
    const u32 m = wave_min_u32(m0 < m1 ? m0 : m1);
    // exact tie-break: min idx among entries with kd == m
    u32 ci = 0xFFFFFFFFu;
#pragma unroll
    for (int t = 0; t < 4; ++t) {
      const u32 cm = (ki[t] < ci) ? ki[t] : ci;
      ci = (kd[t] == m) ? cm : ci;
    }
    const u32 wi = wave_min_u32(ci);
    if (e == 0) pad = wi;  // centroid itself (d2 = 0) is always valid
    const u32 sel = (m == 0xFFFFFFFFu) ? pad : wi;
    if (lane == e) my = sel;
    // scrub winner by its globally-unique index
#pragma unroll
    for (int t = 0; t < 4; ++t)
      if (ki[t] == wi) kd[t] = 0xFFFFFFFFu;
  }
  if (lane < 32) nbr[(size_t)sg * NK + lane] = (int)my;
}

// ---------------- K3: gather -> bf16 MFMA MLP (swapped operands) -> maxpool ----
// mfma(W_frag, A_frag, acc) computes the transposed tile: lane l holds 4
// consecutive-n outputs for m = l&15  ->  packed b64 Hs stores (layer 1) and
// DPP row_shr maxpool + dwordx4 out stores (layer 2). Fragment loads unchanged.
__global__ __launch_bounds__(256) void mlp_kernel(
    const float* __restrict__ x, const float* __restrict__ pos,
    const float* __restrict__ b1, const float* __restrict__ b2,
    const int* __restrict__ nbr, const u16* __restrict__ W1T,
    const u16* __restrict__ W2T, const float* __restrict__ pos_s,
    float* __restrict__ out) {
  __shared__ u16 A[128 * LDA];
  __shared__ u16 Hs[128 * LDH];
  const int ctr0 = blockIdx.x * 4;
  const int b = ctr0 >> 10;
  const int tid = threadIdx.x;
  {  // stage A tile: 128 rows x 96 cols bf16 (x | rel | zeros)
    const int row = tid >> 1, half = tid & 1;
    const int g = ctr0 + (row >> 5);
    const int n = nbr[(size_t)g * NK + (row & 31)];
    const float4* xr = (const float4*)(x + ((size_t)b * NP + n) * NCH + half * 32);
#pragma unroll
    for (int qq = 0; qq < 4; ++qq) {
      const float4 v0 = xr[2 * qq], v1 = xr[2 * qq + 1];
      uint4 wp;
      wp.x = (u32)f2bf(v0.x) | ((u32)f2bf(v0.y) << 16);
      wp.y = (u32)f2bf(v0.z) | ((u32)f2bf(v0.w) << 16);
      wp.z = (u32)f2bf(v1.x) | ((u32)f2bf(v1.y) << 16);
      wp.w = (u32)f2bf(v1.z) | ((u32)f2bf(v1.w) << 16);
      *(uint4*)&A[row * LDA + half * 32 + qq * 8] = wp;
    }
    if (half == 0) {
      const float rx = pos[((size_t)b * NP + n) * 3 + 0] - pos_s[(size_t)g * 3 + 0];
      const float ry = pos[((size_t)b * NP + n) * 3 + 1] - pos_s[(size_t)g * 3 + 1];
      const float rz = pos[((size_t)b * NP + n) * 3 + 2] - pos_s[(size_t)g * 3 + 2];
      uint4 wr;
      wr.x = (u32)f2bf(rx) | ((u32)f2bf(ry) << 16);
      wr.y = (u32)f2bf(rz);
      wr.z = 0; wr.w = 0;
      uint4 wz;
      wz.x = wz.y = wz.z = wz.w = 0;
      *(uint4*)&A[row * LDA + 64] = wr;
      *(uint4*)&A[row * LDA + 72] = wz;
      *(uint4*)&A[row * LDA + 80] = wz;
      *(uint4*)&A[row * LDA + 88] = wz;
    }
  }
  __syncthreads();
  const int lane = tid & 63, w = tid >> 6;
  const int r16 = lane & 15, g4 = lane >> 4;
  {  // layer 1: h^T tiles = W1T-frag x A-frag; lane l: m = l&15, n = g4*4+r
    bfrag af[2][3];
#pragma unroll
    for (int mg2 = 0; mg2 < 2; ++mg2)
#pragma unroll
      for (int ks = 0; ks < 3; ++ks)
        af[mg2][ks] = *(const bfrag*)&A[((2 * w + mg2) * 16 + r16) * LDA + ks * 32 + g4 * 8];
#pragma unroll
    for (int ng = 0; ng < 8; ++ng) {
      const bfrag bw0 = *(const bfrag*)&W1T[(ng * 16 + r16) * KP1 + 0 + g4 * 8];
      const bfrag bw1 = *(const bfrag*)&W1T[(ng * 16 + r16) * KP1 + 32 + g4 * 8];
      const bfrag bw2 = *(const bfrag*)&W1T[(ng * 16 + r16) * KP1 + 64 + g4 * 8];
      facc4 a0 = {0.f, 0.f, 0.f, 0.f}, a1 = {0.f, 0.f, 0.f, 0.f};
      a0 = __builtin_amdgcn_mfma_f32_16x16x32_bf16(bw0, af[0][0], a0, 0, 0, 0);
      a0 = __builtin_amdgcn_mfma_f32_16x16x32_bf16(bw1, af[0][1], a0, 0, 0, 0);
      a0 = __builtin_amdgcn_mfma_f32_16x16x32_bf16(bw2, af[0][2], a0, 0, 0, 0);
      a1 = __builtin_amdgcn_mfma_f32_16x16x32_bf16(bw0, af[1][0], a1, 0, 0, 0);
      a1 = __builtin_amdgcn_mfma_f32_16x16x32_bf16(bw1, af[1][1], a1, 0, 0, 0);
      a1 = __builtin_amdgcn_mfma_f32_16x16x32_bf16(bw2, af[1][2], a1, 0, 0, 0);
      const float4 bias4 = *(const float4*)&b1[ng * 16 + g4 * 4];
      const int nb = ng * 16 + g4 * 4;
      u32 lo0 = (u32)f2bf(fmaxf(a0[0] + bias4.x, 0.f)) | ((u32)f2bf(fmaxf(a0[1] + bias4.y, 0.f)) << 16);
      u32 hi0 = (u32)f2bf(fmaxf(a0[2] + bias4.z, 0.f)) | ((u32)f2bf(fmaxf(a0[3] + bias4.w, 0.f)) << 16);
      u32 lo1 = (u32)f2bf(fmaxf(a1[0] + bias4.x, 0.f)) | ((u32)f2bf(fmaxf(a1[1] + bias4.y, 0.f)) << 16);
      u32 hi1 = (u32)f2bf(fmaxf(a1[2] + bias4.z, 0.f)) | ((u32)f2bf(fmaxf(a1[3] + bias4.w, 0.f)) << 16);
      *(uint2*)&Hs[((2 * w + 0) * 16 + r16) * LDH + nb] = make_uint2(lo0, hi0);
      *(uint2*)&Hs[((2 * w + 1) * 16 + r16) * LDH + nb] = make_uint2(lo1, hi1);
    }
  }
  __syncthreads();
  {  // layer 2 + maxpool: wave w owns centroid w (m rows 32w..32w+31)
    bfrag hf[2][4];
#pragma unroll
    for (int mg2 = 0; mg2 < 2; ++mg2)
#pragma unroll
      for (int ks = 0; ks < 4; ++ks)
        hf[mg2][ks] = *(const bfrag*)&Hs[((2 * w + mg2) * 16 + r16) * LDH + ks * 32 + g4 * 8];
    const int gout = ctr0 + w;
    const int NI = (int)0xFF800000u;  // -inf
#pragma unroll
    for (int ng = 0; ng < 16; ++ng) {
      facc4 a0 = {0.f, 0.f, 0.f, 0.f}, a1 = {0.f, 0.f, 0.f, 0.f};
#pragma unroll
      for (int ks = 0; ks < 4; ++ks) {
        const bfrag bw = *(const bfrag*)&W2T[(ng * 16 + r16) * H1D + ks * 32 + g4 * 8];
        a0 = __builtin_amdgcn_mfma_f32_16x16x32_bf16(bw, hf[0][ks], a0, 0, 0, 0);
        a1 = __builtin_amdgcn_mfma_f32_16x16x32_bf16(bw, hf[1][ks], a1, 0, 0, 0);
      }
      float v0 = fmaxf(a0[0], a1[0]);
      float v1 = fmaxf(a0[1], a1[1]);
      float v2 = fmaxf(a0[2], a1[2]);
      float v3 = fmaxf(a0[3], a1[3]);
      // max over the 16 m-lanes of each group: row_shr 1/2/4/8 -> lane 15 has max
#pragma unroll
      for (int s = 0; s < 4; ++s) {
        const int ctrl = 0x111 << s ? 0 : 0;  // placeholder (real ctrl below)
        (void)ctrl;
      }
      v0 = fmaxf(v0, __int_as_float(__builtin_amdgcn_update_dpp(NI, __float_as_int(v0), 0x111, 0xf, 0xf, false)));
      v1 = fmaxf(v1, __int_as_float(__builtin_amdgcn_update_dpp(NI, __float_as_int(v1), 0x111, 0xf, 0xf, false)));
      v2 = fmaxf(v2, __int_as_float(__builtin_amdgcn_update_dpp(NI, __float_as_int(v2), 0x111, 0xf, 0xf, false)));
      v3 = fmaxf(v3, __int_as_float(__builtin_amdgcn_update_dpp(NI, __float_as_int(v3), 0x111, 0xf, 0xf, false)));
      v0 = fmaxf(v0, __int_as_float(__builtin_amdgcn_update_dpp(NI, __float_as_int(v0), 0x112, 0xf, 0xf, false)));
      v1 = fmaxf(v1, __int_as_float(__builtin_amdgcn_update_dpp(NI, __float_as_int(v1), 0x112, 0xf, 0xf, false)));
      v2 = fmaxf(v2, __int_as_float(__builtin_amdgcn_update_dpp(NI, __float_as_int(v2), 0x112, 0xf, 0xf, false)));
      v3 = fmaxf(v3, __int_as_float(__builtin_amdgcn_update_dpp(NI, __float_as_int(v3), 0x112, 0xf, 0xf, false)));
      v0 = fmaxf(v0, __int_as_float(__builtin_amdgcn_update_dpp(NI, __float_as_int(v0), 0x114, 0xf, 0xf, false)));
      v1 = fmaxf(v1, __int_as_float(__builtin_amdgcn_update_dpp(NI, __float_as_int(v1), 0x114, 0xf, 0xf, false)));
      v2 = fmaxf(v2, __int_as_float(__builtin_amdgcn_update_dpp(NI, __float_as_int(v2), 0x114, 0xf, 0xf, false)));
      v3 = fmaxf(v3, __int_as_float(__builtin_amdgcn_update_dpp(NI, __float_as_int(v3), 0x114, 0xf, 0xf, false)));
      v0 = fmaxf(v0, __int_as_float(__builtin_amdgcn_update_dpp(NI, __float_as_int(v0), 0x118, 0xf, 0xf, false)));
      v1 = fmaxf(v1, __int_as_float(__builtin_amdgcn_update_dpp(NI, __float_as_int(v1), 0x118, 0xf, 0xf, false)));
      v2 = fmaxf(v2, __int_as_float(__builtin_amdgcn_update_dpp(NI, __float_as_int(v2), 0x118, 0xf, 0xf, false)));
      v3 = fmaxf(v3, __int_as_float(__builtin_amdgcn_update_dpp(NI, __float_as_int(v3), 0x118, 0xf, 0xf, false)));
      if ((lane & 15) == 15) {
        const float4 b24 = *(const float4*)&b2[ng * 16 + g4 * 4];
        float4 o;
        o.x = fmaxf(v0 + b24.x, 0.f);
        o.y = fmaxf(v1 + b24.y, 0.f);
        o.z = fmaxf(v2 + b24.z, 0.f);
        o.w = fmaxf(v3 + b24.w, 0.f);
        *(float4*)&out[(size_t)gout * H2D + ng * 16 + g4 * 4] = o;
      }
    }
  }
}

extern "C" void kernel_launch(void* const* d_in, const int* in_sizes, int n_in,
                              void* d_out, int out_size, void* d_ws, size_t ws_size,
                              hipStream_t stream) {
  const float* x = (const float*)d_in[0];
  const float* pos = (const float*)d_in[1];
  const float* W1 = (const float*)d_in[2];
  const float* b1 = (const float*)d_in[3];
  const float* W2 = (const float*)d_in[4];
  const float* b2 = (const float*)d_in[5];
  float* out = (float*)d_out;
  char* ws = (char*)d_ws;
  u16* W1T = (u16*)(ws + 0);           // 24576 B
  u16* W2T = (u16*)(ws + 24576);       // 65536 B
  int* samp = (int*)(ws + 90112);      // 65536 B
  int* nbr = (int*)(ws + 155648);      // 2 MiB
  float* pos_s = out + OUTOFF;

  setup_kernel<<<dim3(176), dim3(256), 0, stream>>>(W1, W2, W1T, W2T);
  fps_kernel<<<dim3(NB), dim3(256), 0, stream>>>(pos, samp, pos_s);
  ballq_kernel<<<dim3(NB * NS / 4), dim3(256), 0, stream>>>(pos, samp, nbr);
  mlp_kernel<<<dim3(NB * NS / 4), dim3(256), 0, stream>>>(x, pos, b1, b2, nbr, W1T, W2T,
                                                          pos_s, out);
}

// Round 8
// 917.778 us; speedup vs baseline: 1.5828x; 1.0044x over previous
//
#include <hip/hip_runtime.h>
#include <stdint.h>

typedef unsigned short u16;
typedef unsigned int u32;
typedef unsigned long long u64;

#define NB 16
#define NP 4096
#define NCH 64
#define NS 1024
#define NK 32
#define H1D 128
#define H2D 256
#define KP1 96
#define LDA 104
#define LDH 136
#define OUTOFF (NB * NS * H2D) /* 4194304 */

typedef __attribute__((ext_vector_type(8))) short bfrag;
typedef __attribute__((ext_vector_type(4))) float facc4;
typedef __attribute__((ext_vector_type(2))) float f32x2;

__device__ __forceinline__ u16 f2bf(float f) {
  u32 u = __float_as_uint(f);
  u += 0x7FFFu + ((u >> 16) & 1u);
  return (u16)(u >> 16);
}

// Exactly replicates jnp.sum((a-b)**2, axis=-1) for 3 elems: ((dx*dx+dy*dy)+dz*dz),
// no fma contraction (XLA emits plain mul/add; hipcc honors the pragma).
__device__ __forceinline__ float dist2(float ax, float ay, float az,
                                       float bx, float by, float bz) {
#pragma clang fp contract(off)
  float dx = ax - bx, dy = ay - by, dz = az - bz;
  return dx * dx + dy * dy + dz * dz;
}

// Pairwise dist2: identical per-element IEEE arithmetic, packed f32x2 ops
// (gfx950 v_pk_add/mul_f32 halve the issue count when the backend forms them).
__device__ __forceinline__ f32x2 dist2v(f32x2 ax, f32x2 ay, f32x2 az,
                                        float bx, float by, float bz) {
#pragma clang fp contract(off)
  f32x2 dx = ax - bx, dy = ay - by, dz = az - bz;
  return dx * dx + dy * dy + dz * dz;
}

// Full-wave (64-lane) max via DPP on the VALU pipe; result returned uniform.
__device__ __forceinline__ float wave_max_f32(float v) {
  const int NI = (int)0xFF800000u;  // -inf bits = identity for max
  v = fmaxf(v, __int_as_float(__builtin_amdgcn_update_dpp(NI, __float_as_int(v), 0x111, 0xf, 0xf, false)));
  v = fmaxf(v, __int_as_float(__builtin_amdgcn_update_dpp(NI, __float_as_int(v), 0x112, 0xf, 0xf, false)));
  v = fmaxf(v, __int_as_float(__builtin_amdgcn_update_dpp(NI, __float_as_int(v), 0x114, 0xf, 0xf, false)));
  v = fmaxf(v, __int_as_float(__builtin_amdgcn_update_dpp(NI, __float_as_int(v), 0x118, 0xf, 0xf, false)));
  v = fmaxf(v, __int_as_float(__builtin_amdgcn_update_dpp(NI, __float_as_int(v), 0x142, 0xa, 0xf, false)));
  v = fmaxf(v, __int_as_float(__builtin_amdgcn_update_dpp(NI, __float_as_int(v), 0x143, 0xc, 0xf, false)));
  return __int_as_float(__builtin_amdgcn_readlane(__float_as_int(v), 63));
}

// Full-wave (64-lane) min of u32 via DPP; result returned uniform. (used by ballq)
__device__ __forceinline__ u32 wave_min_u32(u32 v) {
  u32 t;
  t = (u32)__builtin_amdgcn_update_dpp(-1, (int)v, 0x111, 0xf, 0xf, false); v = t < v ? t : v;
  t = (u32)__builtin_amdgcn_update_dpp(-1, (int)v, 0x112, 0xf, 0xf, false); v = t < v ? t : v;
  t = (u32)__builtin_amdgcn_update_dpp(-1, (int)v, 0x114, 0xf, 0xf, false); v = t < v ? t : v;
  t = (u32)__builtin_amdgcn_update_dpp(-1, (int)v, 0x118, 0xf, 0xf, false); v = t < v ? t : v;
  t = (u32)__builtin_amdgcn_update_dpp(-1, (int)v, 0x142, 0xa, 0xf, false); v = t < v ? t : v;
  t = (u32)__builtin_amdgcn_update_dpp(-1, (int)v, 0x143, 0xc, 0xf, false); v = t < v ? t : v;
  return (u32)__builtin_amdgcn_readlane((int)v, 63);
}

// One step of a 4-slot quad_perm butterfly carrying (key, x, y, z).
#define QUAD_MAX_STEP(CTRL)                                                           \
  {                                                                                   \
    const u32 plo = (u32)__builtin_amdgcn_update_dpp(0, (int)klo, (CTRL), 0xf, 0xf, true); \
    const u32 phi = (u32)__builtin_amdgcn_update_dpp(0, (int)khi, (CTRL), 0xf, 0xf, true); \
    const u32 pqx = (u32)__builtin_amdgcn_update_dpp(0, (int)qxu, (CTRL), 0xf, 0xf, true); \
    const u32 pqy = (u32)__builtin_amdgcn_update_dpp(0, (int)qyu, (CTRL), 0xf, 0xf, true); \
    const u32 pqz = (u32)__builtin_amdgcn_update_dpp(0, (int)qzu, (CTRL), 0xf, 0xf, true); \
    const u64 ok = ((u64)phi << 32) | plo;                                            \
    const u64 mk = ((u64)khi << 32) | klo;                                            \
    if (ok > mk) { klo = plo; khi = phi; qxu = pqx; qyu = pqy; qzu = pqz; }           \
  }

// ---------------- K0: transpose + pad + bf16-convert weights ----------------
__global__ void setup_kernel(const float* __restrict__ W1, const float* __restrict__ W2,
                             u16* __restrict__ W1T, u16* __restrict__ W2T) {
  int idx = blockIdx.x * 256 + threadIdx.x;
  if (idx < H1D * KP1) {
    int n = idx / KP1, k = idx % KP1;
    W1T[idx] = f2bf(k < 67 ? W1[k * H1D + n] : 0.f);
  } else if (idx < H1D * KP1 + H2D * H1D) {
    int j = idx - H1D * KP1;
    int n = j / H1D, k = j % H1D;
    W2T[j] = f2bf(W2[k * H2D + n]);
  }
}

// ---------------- K1: farthest point sampling (1 block per cloud) ----------------
// 256 threads = 4 waves (1/SIMD); 16 CONSECUTIVE pts/thread (p = tid*16+j), so
// among tied lanes min global index == lowest lane -> ballot+first-set-lane
// replaces the second DPP chain. Winner lane publishes {key,x,y,z} (its pos was
// speculatively read under the value-max chain); post-barrier 2-step quad_perm
// butterfly resolves 4 wave records with no dependent plds[gi] read.
__global__ __launch_bounds__(256) void fps_kernel(const float* __restrict__ pos,
                                                  int* __restrict__ samp,
                                                  float* __restrict__ pos_s) {
  __shared__ float4 plds[NP];                  // 64 KiB: pos as float4
  __shared__ __align__(16) u32 recs[2][4][8];  // 2 buf x 4 waves x 20B record
  const int b = blockIdx.x;
  const int tid = threadIdx.x;
  const int lane = tid & 63, wv = tid >> 6;
  const float* pb = pos + (size_t)b * NP * 3;
  for (int k = tid; k < NP; k += 256)
    plds[k] = make_float4(pb[k * 3 + 0], pb[k * 3 + 1], pb[k * 3 + 2], 0.f);
  __syncthreads();

  f32x2 px2[8], py2[8], pz2[8], dd[8];
  const float4 q0 = plds[0];
  float bv = -1.f;
  int bj = 0;
#pragma unroll
  for (int t = 0; t < 8; ++t) {
    const float4 pA = plds[tid * 16 + 2 * t];      // one-time conflicty staging,
    const float4 pB = plds[tid * 16 + 2 * t + 1];  // amortized over 1023 iters
    px2[t] = (f32x2){pA.x, pB.x};
    py2[t] = (f32x2){pA.y, pB.y};
    pz2[t] = (f32x2){pA.z, pB.z};
    const f32x2 s = dist2v(px2[t], py2[t], pz2[t], q0.x, q0.y, q0.z);
    dd[t] = s;
    // ascending p = tid*16 + 2t(+1); strict > => first occurrence
    const bool c0 = s.x > bv; bv = c0 ? s.x : bv; bj = c0 ? 2 * t : bj;
    const bool c1 = s.y > bv; bv = c1 ? s.y : bv; bj = c1 ? 2 * t + 1 : bj;
  }
  if (tid == 0) {
    samp[b * NS] = 0;
    pos_s[(size_t)b * NS * 3 + 0] = q0.x;
    pos_s[(size_t)b * NS * 3 + 1] = q0.y;
    pos_s[(size_t)b * NS * 3 + 2] = q0.z;
  }

  for (int i = 1; i < NS; ++i) {
    const int gidx = tid * 16 + bj;
    const float4 cpos = plds[gidx];  // speculative; hides under the DPP chain
    const float wmax = wave_max_f32(bv);
    // winner = first (lowest) lane with bv == wmax  ==  min gidx among ties
    const u64 mask = __ballot(bv == wmax);
    const bool winner = (bv == wmax) && ((mask & ((1ull << lane) - 1ull)) == 0ull);
    if (winner) {
      u32* rp = &recs[i & 1][wv][0];
      *(uint4*)rp = make_uint4(4095u - (u32)gidx, __float_as_uint(bv),
                               __float_as_uint(cpos.x), __float_as_uint(cpos.y));
      rp[4] = __float_as_uint(cpos.z);
    }
    __syncthreads();
    // all lanes: read record (lane&3), 2-step quad butterfly -> uniform winner
    const u32* sp = &recs[i & 1][lane & 3][0];
    const uint4 rA = *(const uint4*)sp;
    u32 klo = rA.x, khi = rA.y, qxu = rA.z, qyu = rA.w, qzu = sp[4];
    QUAD_MAX_STEP(0xB1)  // quad_perm [1,0,3,2]
    QUAD_MAX_STEP(0x4E)  // quad_perm [2,3,0,1]
    const float qx = __uint_as_float(qxu);
    const float qy = __uint_as_float(qyu);
    const float qz = __uint_as_float(qzu);
    if (tid == 0) {
      samp[b * NS + i] = 4095 - (int)(klo & 0xFFFu);
      pos_s[((size_t)b * NS + i) * 3 + 0] = qx;
      pos_s[((size_t)b * NS + i) * 3 + 1] = qy;
      pos_s[((size_t)b * NS + i) * 3 + 2] = qz;
    }
    // fused d-update (packed) + next local argmax (scalar on halves)
    bv = -1.f; bj = 0;
#pragma unroll
    for (int t = 0; t < 8; ++t) {
      const f32x2 s = dist2v(px2[t], py2[t], pz2[t], qx, qy, qz);
      dd[t].x = fminf(dd[t].x, s.x);
      dd[t].y = fminf(dd[t].y, s.y);
      const bool c0 = dd[t].x > bv; bv = c0 ? dd[t].x : bv; bj = c0 ? 2 * t : bj;
      const bool c1 = dd[t].y > bv; bv = c1 ? dd[t].y : bv; bj = c1 ? 2 * t + 1 : bj;
    }
  }
}

// ---------------- K2: ball query, exact top-K=32 by (d2, idx) key ----------------
// u32 split-key extraction: DPP v_min_u32 chains (VALU) replace the u64
// shfl_xor butterfly (LDS pipe). Tie-break remains exact lexicographic.
__global__ __launch_bounds__(256) void ballq_kernel(const float* __restrict__ pos,
                                                    const int* __restrict__ samp,
                                                    int* __restrict__ nbr) {
  __shared__ u64 buf[4][256];
  const int lane = threadIdx.x & 63, wv = threadIdx.x >> 6;
  const int sg = blockIdx.x * 4 + wv;
  const int b = sg >> 10;
  const int nc = samp[sg];
  const float* pb = pos + (size_t)b * NP * 3;
  const float cx = pb[nc * 3 + 0], cy = pb[nc * 3 + 1], cz = pb[nc * 3 + 2];
  const float r2 = (float)(0.2 * 0.2);  // matches Python RADIUS*RADIUS -> f32
  int V = 0;
  for (int c = 0; c < 64; ++c) {
    const int i = c * 64 + lane;
    const float d2v = dist2(cx, cy, cz, pb[i * 3 + 0], pb[i * 3 + 1], pb[i * 3 + 2]);
    const bool valid = d2v <= r2;
    const u64 bal = __ballot(valid);
    if (valid) {
      const int rank = __popcll(bal & ((1ull << lane) - 1ull));
      const int p = V + rank;
      if (p < 256) buf[wv][p] = ((u64)__float_as_uint(d2v) << 32) | (u32)i;
    }
    V += __popcll(bal);
  }
  if (V > 256) V = 256;  // P(V>256) ~ 1e-21 per query (mean 137, sd 11.5)
  u32 kd[4], ki[4];
#pragma unroll
  for (int t = 0; t < 4; ++t) {
    const int p = t * 64 + lane;
    const u64 v = (p < V) ? buf[wv][p] : ~0ull;
    kd[t] = (u32)(v >> 32);
    ki[t] = (u32)v;
  }
  u32 my = 0, pad = 0;
  for (int e = 0; e < 32; ++e) {
    // global min d2-bits
    u32 m0 = kd[0] < kd[1] ? kd[0] : kd[1];
    u32 m1 = kd[2] < kd[3] ? kd[2] : kd[3];
    const u32 m = wave_min_u32(m0 < m1 ? m0 : m1);
    // exact tie-break: min idx among entries with kd == m
    u32 ci = 0xFFFFFFFFu;
#pragma unroll
    for (int t = 0; t < 4; ++t) {
      const u32 cm = (ki[t] < ci) ? ki[t] : ci;
      ci = (kd[t] == m) ? cm : ci;
    }
    const u32 wi = wave_min_u32(ci);
    if (e == 0) pad = wi;  // centroid itself (d2 = 0) is always valid
    const u32 sel = (m == 0xFFFFFFFFu) ? pad : wi;
    if (lane == e) my = sel;
    // scrub winner by its globally-unique index
#pragma unroll
    for (int t = 0; t < 4; ++t)
      if (ki[t] == wi) kd[t] = 0xFFFFFFFFu;
  }
  if (lane < 32) nbr[(size_t)sg * NK + lane] = (int)my;
}

// ---------------- K3: gather -> bf16 MFMA MLP (swapped operands) -> maxpool ----
// mfma(W_frag, A_frag, acc) computes the transposed tile: lane l holds 4
// consecutive-n outputs for m = l&15  ->  packed b64 Hs stores (layer 1) and
// DPP row_shr maxpool + dwordx4 out stores (layer 2). Fragment loads unchanged.
__global__ __launch_bounds__(256) void mlp_kernel(
    const float* __restrict__ x, const float* __restrict__ pos,
    const float* __restrict__ b1, const float* __restrict__ b2,
    const int* __restrict__ nbr, const u16* __restrict__ W1T,
    const u16* __restrict__ W2T, const float* __restrict__ pos_s,
    float* __restrict__ out) {
  __shared__ u16 A[128 * LDA];
  __shared__ u16 Hs[128 * LDH];
  const int ctr0 = blockIdx.x * 4;
  const int b = ctr0 >> 10;
  const int tid = threadIdx.x;
  {  // stage A tile: 128 rows x 96 cols bf16 (x | rel | zeros)
    const int row = tid >> 1, half = tid & 1;
    const int g = ctr0 + (row >> 5);
    const int n = nbr[(size_t)g * NK + (row & 31)];
    const float4* xr = (const float4*)(x + ((size_t)b * NP + n) * NCH + half * 32);
#pragma unroll
    for (int qq = 0; qq < 4; ++qq) {
      const float4 v0 = xr[2 * qq], v1 = xr[2 * qq + 1];
      uint4 wp;
      wp.x = (u32)f2bf(v0.x) | ((u32)f2bf(v0.y) << 16);
      wp.y = (u32)f2bf(v0.z) | ((u32)f2bf(v0.w) << 16);
      wp.z = (u32)f2bf(v1.x) | ((u32)f2bf(v1.y) << 16);
      wp.w = (u32)f2bf(v1.z) | ((u32)f2bf(v1.w) << 16);
      *(uint4*)&A[row * LDA + half * 32 + qq * 8] = wp;
    }
    if (half == 0) {
      const float rx = pos[((size_t)b * NP + n) * 3 + 0] - pos_s[(size_t)g * 3 + 0];
      const float ry = pos[((size_t)b * NP + n) * 3 + 1] - pos_s[(size_t)g * 3 + 1];
      const float rz = pos[((size_t)b * NP + n) * 3 + 2] - pos_s[(size_t)g * 3 + 2];
      uint4 wr;
      wr.x = (u32)f2bf(rx) | ((u32)f2bf(ry) << 16);
      wr.y = (u32)f2bf(rz);
      wr.z = 0; wr.w = 0;
      uint4 wz;
      wz.x = wz.y = wz.z = wz.w = 0;
      *(uint4*)&A[row * LDA + 64] = wr;
      *(uint4*)&A[row * LDA + 72] = wz;
      *(uint4*)&A[row * LDA + 80] = wz;
      *(uint4*)&A[row * LDA + 88] = wz;
    }
  }
  __syncthreads();
  const int lane = tid & 63, w = tid >> 6;
  const int r16 = lane & 15, g4 = lane >> 4;
  {  // layer 1: h^T tiles = W1T-frag x A-frag; lane l: m = l&15, n = g4*4+r
    bfrag af[2][3];
#pragma unroll
    for (int mg2 = 0; mg2 < 2; ++mg2)
#pragma unroll
      for (int ks = 0; ks < 3; ++ks)
        af[mg2][ks] = *(const bfrag*)&A[((2 * w + mg2) * 16 + r16) * LDA + ks * 32 + g4 * 8];
#pragma unroll
    for (int ng = 0; ng < 8; ++ng) {
      const bfrag bw0 = *(const bfrag*)&W1T[(ng * 16 + r16) * KP1 + 0 + g4 * 8];
      const bfrag bw1 = *(const bfrag*)&W1T[(ng * 16 + r16) * KP1 + 32 + g4 * 8];
      const bfrag bw2 = *(const bfrag*)&W1T[(ng * 16 + r16) * KP1 + 64 + g4 * 8];
      facc4 a0 = {0.f, 0.f, 0.f, 0.f}, a1 = {0.f, 0.f, 0.f, 0.f};
      a0 = __builtin_amdgcn_mfma_f32_16x16x32_bf16(bw0, af[0][0], a0, 0, 0, 0);
      a0 = __builtin_amdgcn_mfma_f32_16x16x32_bf16(bw1, af[0][1], a0, 0, 0, 0);
      a0 = __builtin_amdgcn_mfma_f32_16x16x32_bf16(bw2, af[0][2], a0, 0, 0, 0);
      a1 = __builtin_amdgcn_mfma_f32_16x16x32_bf16(bw0, af[1][0], a1, 0, 0, 0);
      a1 = __builtin_amdgcn_mfma_f32_16x16x32_bf16(bw1, af[1][1], a1, 0, 0, 0);
      a1 = __builtin_amdgcn_mfma_f32_16x16x32_bf16(bw2, af[1][2], a1, 0, 0, 0);
      const float4 bias4 = *(const float4*)&b1[ng * 16 + g4 * 4];
      const int nb = ng * 16 + g4 * 4;
      u32 lo0 = (u32)f2bf(fmaxf(a0[0] + bias4.x, 0.f)) | ((u32)f2bf(fmaxf(a0[1] + bias4.y, 0.f)) << 16);
      u32 hi0 = (u32)f2bf(fmaxf(a0[2] + bias4.z, 0.f)) | ((u32)f2bf(fmaxf(a0[3] + bias4.w, 0.f)) << 16);
      u32 lo1 = (u32)f2bf(fmaxf(a1[0] + bias4.x, 0.f)) | ((u32)f2bf(fmaxf(a1[1] + bias4.y, 0.f)) << 16);
      u32 hi1 = (u32)f2bf(fmaxf(a1[2] + bias4.z, 0.f)) | ((u32)f2bf(fmaxf(a1[3] + bias4.w, 0.f)) << 16);
      *(uint2*)&Hs[((2 * w + 0) * 16 + r16) * LDH + nb] = make_uint2(lo0, hi0);
      *(uint2*)&Hs[((2 * w + 1) * 16 + r16) * LDH + nb] = make_uint2(lo1, hi1);
    }
  }
  __syncthreads();
  {  // layer 2 + maxpool: wave w owns centroid w (m rows 32w..32w+31)
    bfrag hf[2][4];
#pragma unroll
    for (int mg2 = 0; mg2 < 2; ++mg2)
#pragma unroll
      for (int ks = 0; ks < 4; ++ks)
        hf[mg2][ks] = *(const bfrag*)&Hs[((2 * w + mg2) * 16 + r16) * LDH + ks * 32 + g4 * 8];
    const int gout = ctr0 + w;
    const int NI = (int)0xFF800000u;  // -inf
#pragma unroll
    for (int ng = 0; ng < 16; ++ng) {
      facc4 a0 = {0.f, 0.f, 0.f, 0.f}, a1 = {0.f, 0.f, 0.f, 0.f};
#pragma unroll
      for (int ks = 0; ks < 4; ++ks) {
        const bfrag bw = *(const bfrag*)&W2T[(ng * 16 + r16) * H1D + ks * 32 + g4 * 8];
        a0 = __builtin_amdgcn_mfma_f32_16x16x32_bf16(bw, hf[0][ks], a0, 0, 0, 0);
        a1 = __builtin_amdgcn_mfma_f32_16x16x32_bf16(bw, hf[1][ks], a1, 0, 0, 0);
      }
      float v0 = fmaxf(a0[0], a1[0]);
      float v1 = fmaxf(a0[1], a1[1]);
      float v2 = fmaxf(a0[2], a1[2]);
      float v3 = fmaxf(a0[3], a1[3]);
      // max over the 16 m-lanes of each group: row_shr 1/2/4/8 -> lane 15 has max
      v0 = fmaxf(v0, __int_as_float(__builtin_amdgcn_update_dpp(NI, __float_as_int(v0), 0x111, 0xf, 0xf, false)));
      v1 = fmaxf(v1, __int_as_float(__builtin_amdgcn_update_dpp(NI, __float_as_int(v1), 0x111, 0xf, 0xf, false)));
      v2 = fmaxf(v2, __int_as_float(__builtin_amdgcn_update_dpp(NI, __float_as_int(v2), 0x111, 0xf, 0xf, false)));
      v3 = fmaxf(v3, __int_as_float(__builtin_amdgcn_update_dpp(NI, __float_as_int(v3), 0x111, 0xf, 0xf, false)));
      v0 = fmaxf(v0, __int_as_float(__builtin_amdgcn_update_dpp(NI, __float_as_int(v0), 0x112, 0xf, 0xf, false)));
      v1 = fmaxf(v1, __int_as_float(__builtin_amdgcn_update_dpp(NI, __float_as_int(v1), 0x112, 0xf, 0xf, false)));
      v2 = fmaxf(v2, __int_as_float(__builtin_amdgcn_update_dpp(NI, __float_as_int(v2), 0x112, 0xf, 0xf, false)));
      v3 = fmaxf(v3, __int_as_float(__builtin_amdgcn_update_dpp(NI, __float_as_int(v3), 0x112, 0xf, 0xf, false)));
      v0 = fmaxf(v0, __int_as_float(__builtin_amdgcn_update_dpp(NI, __float_as_int(v0), 0x114, 0xf, 0xf, false)));
      v1 = fmaxf(v1, __int_as_float(__builtin_amdgcn_update_dpp(NI, __float_as_int(v1), 0x114, 0xf, 0xf, false)));
      v2 = fmaxf(v2, __int_as_float(__builtin_amdgcn_update_dpp(NI, __float_as_int(v2), 0x114, 0xf, 0xf, false)));
      v3 = fmaxf(v3, __int_as_float(__builtin_amdgcn_update_dpp(NI, __float_as_int(v3), 0x114, 0xf, 0xf, false)));
      v0 = fmaxf(v0, __int_as_float(__builtin_amdgcn_update_dpp(NI, __float_as_int(v0), 0x118, 0xf, 0xf, false)));
      v1 = fmaxf(v1, __int_as_float(__builtin_amdgcn_update_dpp(NI, __float_as_int(v1), 0x118, 0xf, 0xf, false)));
      v2 = fmaxf(v2, __int_as_float(__builtin_amdgcn_update_dpp(NI, __float_as_int(v2), 0x118, 0xf, 0xf, false)));
      v3 = fmaxf(v3, __int_as_float(__builtin_amdgcn_update_dpp(NI, __float_as_int(v3), 0x118, 0xf, 0xf, false)));
      if ((lane & 15) == 15) {
        const float4 b24 = *(const float4*)&b2[ng * 16 + g4 * 4];
        float4 o;
        o.x = fmaxf(v0 + b24.x, 0.f);
        o.y = fmaxf(v1 + b24.y, 0.f);
        o.z = fmaxf(v2 + b24.z, 0.f);
        o.w = fmaxf(v3 + b24.w, 0.f);
        *(float4*)&out[(size_t)gout * H2D + ng * 16 + g4 * 4] = o;
      }
    }
  }
}

extern "C" void kernel_launch(void* const* d_in, const int* in_sizes, int n_in,
                              void* d_out, int out_size, void* d_ws, size_t ws_size,
                              hipStream_t stream) {
  const float* x = (const float*)d_in[0];
  const float* pos = (const float*)d_in[1];
  const float* W1 = (const float*)d_in[2];
  const float* b1 = (const float*)d_in[3];
  const float* W2 = (const float*)d_in[4];
  const float* b2 = (const float*)d_in[5];
  float* out = (float*)d_out;
  char* ws = (char*)d_ws;
  u16* W1T = (u16*)(ws + 0);           // 24576 B
  u16* W2T = (u16*)(ws + 24576);       // 65536 B
  int* samp = (int*)(ws + 90112);      // 65536 B
  int* nbr = (int*)(ws + 155648);      // 2 MiB
  float* pos_s = out + OUTOFF;

  setup_kernel<<<dim3(176), dim3(256), 0, stream>>>(W1, W2, W1T, W2T);
  fps_kernel<<<dim3(NB), dim3(256), 0, stream>>>(pos, samp, pos_s);
  ballq_kernel<<<dim3(NB * NS / 4), dim3(256), 0, stream>>>(pos, samp, nbr);
  mlp_kernel<<<dim3(NB * NS / 4), dim3(256), 0, stream>>>(x, pos, b1, b2, nbr, W1T, W2T,
                                                          pos_s, out);
}